// Round 3
// baseline (107.899 us; speedup 1.0000x reference)
//
#include <hip/hip_runtime.h>
#include <hip/hip_bf16.h>

// Phase 1: per-node dot products s[i] = x[i] . W[0:128], d[i] = x[i] . W[128:256]
// One 64-lane wave per node; lane l handles elements 2l, 2l+1 (coalesced float2).
__global__ void node_dots_kernel(const float* __restrict__ x,
                                 const float* __restrict__ W,
                                 float* __restrict__ s,
                                 float* __restrict__ d,
                                 int N) {
    const int wave = (int)((blockIdx.x * blockDim.x + threadIdx.x) >> 6);
    const int lane = threadIdx.x & 63;
    if (wave >= N) return;

    const float2 xv = *reinterpret_cast<const float2*>(x + (size_t)wave * 128 + lane * 2);
    const float2 ws = *reinterpret_cast<const float2*>(W + lane * 2);          // w_src pair
    const float2 wd = *reinterpret_cast<const float2*>(W + 128 + lane * 2);    // w_dst pair

    float vs = xv.x * ws.x + xv.y * ws.y;
    float vd = xv.x * wd.x + xv.y * wd.y;

    // 64-lane butterfly reduction (wave64!)
    #pragma unroll
    for (int off = 32; off > 0; off >>= 1) {
        vs += __shfl_xor(vs, off);
        vd += __shfl_xor(vd, off);
    }
    if (lane == 0) {
        s[wave] = vs;
        d[wave] = vd;
    }
}

// Phase 2: per-edge score = sigmoid(s[src[e]] + d[dst[e]] + b)
// s/d are 400 KB each -> fully L2-resident; gathers are cheap.
__global__ void edge_score_kernel(const int* __restrict__ src,
                                  const int* __restrict__ dst,
                                  const float* __restrict__ s,
                                  const float* __restrict__ d,
                                  const float* __restrict__ b,
                                  float* __restrict__ out,
                                  int E) {
    const int e = (int)(blockIdx.x * blockDim.x + threadIdx.x);
    if (e >= E) return;
    const float z = s[src[e]] + d[dst[e]] + b[0];
    out[e] = 1.0f / (1.0f + __expf(-z));
}

extern "C" void kernel_launch(void* const* d_in, const int* in_sizes, int n_in,
                              void* d_out, int out_size, void* d_ws, size_t ws_size,
                              hipStream_t stream) {
    const float* x   = (const float*)d_in[0];
    const int*   src = (const int*)d_in[1];
    const int*   dst = (const int*)d_in[2];
    const float* W   = (const float*)d_in[3];
    const float* b   = (const float*)d_in[4];
    float*       out = (float*)d_out;

    const int N = in_sizes[0] / 128;  // 100000
    const int E = in_sizes[1];        // 640000

    // Scratch: s[N], d[N] in workspace (fully overwritten each launch).
    float* s = (float*)d_ws;
    float* d = s + N;

    // Kernel 1: one wave per node, 4 waves (256 threads) per block.
    {
        const int block = 256;
        const int wavesPerBlock = block / 64;
        const int grid = (N + wavesPerBlock - 1) / wavesPerBlock;
        node_dots_kernel<<<grid, block, 0, stream>>>(x, W, s, d, N);
    }

    // Kernel 2: one thread per edge.
    {
        const int block = 256;
        const int grid = (E + block - 1) / block;
        edge_score_kernel<<<grid, block, 0, stream>>>(src, dst, s, d, b, out, E);
    }
}

// Round 4
// 99.425 us; speedup vs baseline: 1.0852x; 1.0852x over previous
//
#include <hip/hip_runtime.h>
#include <hip/hip_bf16.h>

// Phase 1: per-node dots s[i] = x[i].W[0:128], d[i] = x[i].W[128:256].
// 32 lanes per node, float4 per lane (16 B/lane = coalescing sweet spot).
// Each wave64 handles TWO nodes: lanes 0-31 -> node 2w, lanes 32-63 -> node 2w+1.
__global__ void node_dots_v2(const float* __restrict__ x,
                             const float* __restrict__ W,
                             float* __restrict__ s,
                             float* __restrict__ d,
                             int N) {
    const int tid    = (int)(blockIdx.x * blockDim.x + threadIdx.x);
    const int lane   = threadIdx.x & 63;
    const int lane32 = lane & 31;
    const int node   = ((tid >> 6) << 1) + (lane >> 5);  // wave*2 + half
    if (node >= N) return;

    const float4 xv = *reinterpret_cast<const float4*>(x + (size_t)node * 128 + lane32 * 4);
    const float4 ws = *reinterpret_cast<const float4*>(W + lane32 * 4);        // w_src quad
    const float4 wd = *reinterpret_cast<const float4*>(W + 128 + lane32 * 4);  // w_dst quad

    float vs = xv.x * ws.x + xv.y * ws.y + xv.z * ws.z + xv.w * ws.w;
    float vd = xv.x * wd.x + xv.y * wd.y + xv.z * wd.z + xv.w * wd.w;

    // 32-lane butterfly (offsets < 32 stay within each half of the wave64).
    #pragma unroll
    for (int off = 16; off > 0; off >>= 1) {
        vs += __shfl_xor(vs, off);
        vd += __shfl_xor(vd, off);
    }
    if (lane32 == 0) {
        s[node] = vs;
        d[node] = vd;
    }
}

// Phase 2: score[e] = sigmoid(s[src[e]] + d[dst[e]] + b). 4 edges per thread,
// vectorized int4 index loads + float4 stores; gathers hit L2 (s,d = 400 KB each).
__global__ void edge_score_v2(const int* __restrict__ src,
                              const int* __restrict__ dst,
                              const float* __restrict__ s,
                              const float* __restrict__ d,
                              const float* __restrict__ b,
                              float* __restrict__ out,
                              int E4) {  // E/4
    const int t = (int)(blockIdx.x * blockDim.x + threadIdx.x);
    if (t >= E4) return;

    const int4 s4 = reinterpret_cast<const int4*>(src)[t];
    const int4 d4 = reinterpret_cast<const int4*>(dst)[t];
    const float bias = b[0];

    float4 z;
    z.x = s[s4.x] + d[d4.x] + bias;
    z.y = s[s4.y] + d[d4.y] + bias;
    z.z = s[s4.z] + d[d4.z] + bias;
    z.w = s[s4.w] + d[d4.w] + bias;

    float4 o;
    o.x = 1.0f / (1.0f + __expf(-z.x));
    o.y = 1.0f / (1.0f + __expf(-z.y));
    o.z = 1.0f / (1.0f + __expf(-z.z));
    o.w = 1.0f / (1.0f + __expf(-z.w));

    reinterpret_cast<float4*>(out)[t] = o;
}

extern "C" void kernel_launch(void* const* d_in, const int* in_sizes, int n_in,
                              void* d_out, int out_size, void* d_ws, size_t ws_size,
                              hipStream_t stream) {
    const float* x   = (const float*)d_in[0];
    const int*   src = (const int*)d_in[1];
    const int*   dst = (const int*)d_in[2];
    const float* W   = (const float*)d_in[3];
    const float* b   = (const float*)d_in[4];
    float*       out = (float*)d_out;

    const int N = in_sizes[0] / 128;  // 100000
    const int E = in_sizes[1];        // 640000

    float* s = (float*)d_ws;
    float* d = s + N;

    // Kernel 1: 2 nodes per wave -> 8 nodes per 256-thread block.
    {
        const int block = 256;
        const int nodesPerBlock = (block / 64) * 2;
        const int grid = (N + nodesPerBlock - 1) / nodesPerBlock;
        node_dots_v2<<<grid, block, 0, stream>>>(x, W, s, d, N);
    }

    // Kernel 2: 4 edges per thread.
    {
        const int E4 = E / 4;  // E = 640000, divisible by 4
        const int block = 256;
        const int grid = (E4 + block - 1) / block;
        edge_score_v2<<<grid, block, 0, stream>>>(src, dst, s, d, b, out, E4);
    }
}

// Round 8
// 99.386 us; speedup vs baseline: 1.0857x; 1.0004x over previous
//
#include <hip/hip_runtime.h>
#include <hip/hip_bf16.h>

// Native clang vector types — required by __builtin_nontemporal_load/store
// (HIP's int4/float4 are structs and get rejected).
typedef int   vint4   __attribute__((ext_vector_type(4)));
typedef float vfloat4 __attribute__((ext_vector_type(4)));

// Phase 1: per-node dots s[i] = x[i].W[0:128] + b, d[i] = x[i].W[128:256].
// 32 lanes per node, float4 per lane (16 B/lane). Each wave64 handles TWO
// adjacent nodes -> 1 KB contiguous per wave. Bias folded into s.
__global__ __launch_bounds__(256, 8)
void node_dots_v3(const float* __restrict__ x,
                  const float* __restrict__ W,
                  const float* __restrict__ b,
                  float* __restrict__ s,
                  float* __restrict__ d,
                  int N) {
    const int tid    = (int)(blockIdx.x * blockDim.x + threadIdx.x);
    const int lane   = threadIdx.x & 63;
    const int lane32 = lane & 31;
    const int node   = ((tid >> 6) << 1) + (lane >> 5);  // wave*2 + half
    if (node >= N) return;

    const vfloat4 xv = *reinterpret_cast<const vfloat4*>(x + (size_t)node * 128 + lane32 * 4);
    const vfloat4 ws = *reinterpret_cast<const vfloat4*>(W + lane32 * 4);        // w_src quad
    const vfloat4 wd = *reinterpret_cast<const vfloat4*>(W + 128 + lane32 * 4);  // w_dst quad

    float vs = xv.x * ws.x + xv.y * ws.y + xv.z * ws.z + xv.w * ws.w;
    float vd = xv.x * wd.x + xv.y * wd.y + xv.z * wd.z + xv.w * wd.w;

    // 32-lane butterfly (offsets < 32 stay within each half of the wave64).
    #pragma unroll
    for (int off = 16; off > 0; off >>= 1) {
        vs += __shfl_xor(vs, off);
        vd += __shfl_xor(vd, off);
    }
    if (lane32 == 0) {
        s[node] = vs + b[0];   // bias folded in
        d[node] = vd;
    }
}

// Phase 2: score[e] = sigmoid(s[src[e]] + d[dst[e]]). 8 edges per thread:
// 2x int4 per side (nontemporal - single use), 16 independent L2 gathers in
// flight, nontemporal float4 stores (keep L2 for s/d).
__global__ __launch_bounds__(256, 8)
void edge_score_v3(const int* __restrict__ src,
                   const int* __restrict__ dst,
                   const float* __restrict__ s,
                   const float* __restrict__ d,
                   float* __restrict__ out,
                   int E8) {  // E/8
    const int t = (int)(blockIdx.x * blockDim.x + threadIdx.x);
    if (t >= E8) return;

    const vint4* src4 = reinterpret_cast<const vint4*>(src);
    const vint4* dst4 = reinterpret_cast<const vint4*>(dst);
    const vint4 sa = __builtin_nontemporal_load(&src4[2 * t]);
    const vint4 sb = __builtin_nontemporal_load(&src4[2 * t + 1]);
    const vint4 da = __builtin_nontemporal_load(&dst4[2 * t]);
    const vint4 db = __builtin_nontemporal_load(&dst4[2 * t + 1]);

    // Issue all 16 gathers before combining (ILP).
    const float s0 = s[sa.x], s1 = s[sa.y], s2 = s[sa.z], s3 = s[sa.w];
    const float s4 = s[sb.x], s5 = s[sb.y], s6 = s[sb.z], s7 = s[sb.w];
    const float d0 = d[da.x], d1 = d[da.y], d2 = d[da.z], d3 = d[da.w];
    const float d4 = d[db.x], d5 = d[db.y], d6 = d[db.z], d7 = d[db.w];

    vfloat4 oa, ob;
    oa.x = 1.0f / (1.0f + __expf(-(s0 + d0)));
    oa.y = 1.0f / (1.0f + __expf(-(s1 + d1)));
    oa.z = 1.0f / (1.0f + __expf(-(s2 + d2)));
    oa.w = 1.0f / (1.0f + __expf(-(s3 + d3)));
    ob.x = 1.0f / (1.0f + __expf(-(s4 + d4)));
    ob.y = 1.0f / (1.0f + __expf(-(s5 + d5)));
    ob.z = 1.0f / (1.0f + __expf(-(s6 + d6)));
    ob.w = 1.0f / (1.0f + __expf(-(s7 + d7)));

    vfloat4* out4 = reinterpret_cast<vfloat4*>(out);
    __builtin_nontemporal_store(oa, &out4[2 * t]);
    __builtin_nontemporal_store(ob, &out4[2 * t + 1]);
}

extern "C" void kernel_launch(void* const* d_in, const int* in_sizes, int n_in,
                              void* d_out, int out_size, void* d_ws, size_t ws_size,
                              hipStream_t stream) {
    const float* x   = (const float*)d_in[0];
    const int*   src = (const int*)d_in[1];
    const int*   dst = (const int*)d_in[2];
    const float* W   = (const float*)d_in[3];
    const float* b   = (const float*)d_in[4];
    float*       out = (float*)d_out;

    const int N = in_sizes[0] / 128;  // 100000
    const int E = in_sizes[1];        // 640000

    float* s = (float*)d_ws;
    float* d = s + N;

    // Kernel 1: 2 nodes per wave -> 8 nodes per 256-thread block.
    {
        const int block = 256;
        const int nodesPerBlock = (block / 64) * 2;
        const int grid = (N + nodesPerBlock - 1) / nodesPerBlock;
        node_dots_v3<<<grid, block, 0, stream>>>(x, W, b, s, d, N);
    }

    // Kernel 2: 8 edges per thread.
    {
        const int E8 = E / 8;  // 640000 / 8 = 80000
        const int block = 256;
        const int grid = (E8 + block - 1) / block;
        edge_score_v3<<<grid, block, 0, stream>>>(src, dst, s, d, out, E8);
    }
}